// Round 6
// baseline (325.933 us; speedup 1.0000x reference)
//
#include <hip/hip_runtime.h>
#include <math.h>

// PLDA pairwise scorer, eigendecomposition-free, all-symmetric formulation.
// Y ~= S_wn^{-1/2} (NS sqrt), M = Y*SB*Y (symmetric), F = f0(inv_s*M) via
// degree-24 bivariate Chebyshev (T_k(T5(X))*T_r(X), k,r<=4),
// B = (63/64)*inv_s*Y*F*Y.  out = 2 v_i^T B v_j - q_i - q_j - log_div.
// The whole fit runs as ONE 4-block kernel with an agent-scope grid barrier
// between phases (counter reset by k_reduce each launch -> deterministic).

#define D 128
#define NCLS 256
#define NPC 64
#define MTEST 8192
#define COUNT (NCLS*NPC)
#define NBLK 4

// ws float-offset layout (disjoint; U/V are 524288 fl each)
#define fMC    0                      // McT bf16 [128][256] = 16384 fl slots
#define fMEAN  16384                  // 128 f32
#define fSCAL  16640                  // scalars/coefs/partials/barrier (256 f32)
#define fMAT   32768                  // 24 dual-plane matrices x 16384 fl
#define fSWRAW (fMAT + 21*16384)      // slot 21: 16384 f32 Gram sum
#define fPART  425984                 // 64*16384 f32 partials (dead after k_reduce)
#define fU     425984                 // 524288 fl -> ends 950272
#define fV     950272                 // 524288 fl -> ends 1474560
#define fQ     1474560                // 8192 fl
#define fBBF   1482752                // 8192 fl (16384 ushort)

using short8 = __attribute__((ext_vector_type(8))) short;
using f32x4  = __attribute__((ext_vector_type(4))) float;

__device__ inline unsigned short f2bf(float f) {
  unsigned u = __float_as_uint(f);
  unsigned r = u + 0x7FFFu + ((u >> 16) & 1u);
  return (unsigned short)(r >> 16);
}
__device__ inline float bf2f(unsigned short h) {
  return __uint_as_float(((unsigned)h) << 16);
}
__device__ inline float valU(const unsigned short* m, int idx) {
  return bf2f(m[idx]) + bf2f(m[idx + 16384]);
}
__device__ inline void storeDual(unsigned short* m, int idx, float g) {
  unsigned short hb = f2bf(g);
  m[idx] = hb;
  m[16384 + idx] = f2bf(g - bf2f(hb));
}

// agent-scope grid barrier: monotonic counter, 4 blocks
__device__ __forceinline__ void gbar(unsigned* bar, unsigned target) {
  __syncthreads();
  if (threadIdx.x == 0) {
    __hip_atomic_fetch_add(bar, 1u, __ATOMIC_ACQ_REL, __HIP_MEMORY_SCOPE_AGENT);
    while (__hip_atomic_load(bar, __ATOMIC_ACQUIRE, __HIP_MEMORY_SCOPE_AGENT) < target) {
      __builtin_amdgcn_s_sleep(2);
    }
  }
  __syncthreads();
}

// ---------------- K1: Gram partials over 256-row chunks + class means ----------------
__global__ __launch_bounds__(256) void k_gt_partial(const float* __restrict__ X, float* __restrict__ ws) {
  __shared__ unsigned short xt[128 * 256]; // 64 KB, [d][s] swizzled
  int b = blockIdx.x, tid = threadIdx.x;
  const float* Xc = X + b * 256 * D;
  for (int idx = tid; idx < 256 * D; idx += 256) {
    int s = idx >> 7, d = idx & 127;
    unsigned byte = ((unsigned)(d * 512 + s * 2)) ^ (((unsigned)(d & 7)) << 4);
    *(unsigned short*)((char*)xt + byte) = f2bf(Xc[idx]);
  }
  // class means for classes 4b..4b+3 (f32 accumulate from global X)
  {
    int d = tid & 127;
    for (int cc = (tid >> 7); cc < 4; cc += 2) {
      const float* p = Xc + cc * 64 * D + d;
      float s = 0.f;
      #pragma unroll
      for (int n = 0; n < 64; n++) s += p[n * D];
      ((unsigned short*)ws)[d * 256 + (b * 4 + cc)] = f2bf(s * (1.0f / 64.0f));
    }
  }
  __syncthreads();
  int w = tid >> 6, lane = tid & 63;
  int wr = (w >> 1) * 64, wc = (w & 1) * 64;
  f32x4 acc[4][4] = {};
  for (int ks = 0; ks < 8; ks++) {
    int kb = ks * 32 + (lane >> 4) * 8;
    short8 af[4];
    #pragma unroll
    for (int mt = 0; mt < 4; mt++) {
      int r = wr + mt * 16 + (lane & 15);
      unsigned byte = ((unsigned)(r * 512 + kb * 2)) ^ (((unsigned)(r & 7)) << 4);
      af[mt] = *(short8*)((char*)xt + byte);
    }
    #pragma unroll
    for (int nt = 0; nt < 4; nt++) {
      int c = wc + nt * 16 + (lane & 15);
      unsigned byte = ((unsigned)(c * 512 + kb * 2)) ^ (((unsigned)(c & 7)) << 4);
      short8 bfr = *(short8*)((char*)xt + byte);
      #pragma unroll
      for (int mt = 0; mt < 4; mt++)
        acc[mt][nt] = __builtin_amdgcn_mfma_f32_16x16x32_bf16(af[mt], bfr, acc[mt][nt], 0, 0, 0);
    }
  }
  float* outp = ws + fPART + b * 16384;
  #pragma unroll
  for (int mt = 0; mt < 4; mt++)
    #pragma unroll
    for (int nt = 0; nt < 4; nt++)
      #pragma unroll
      for (int r = 0; r < 4; r++) {
        int row = wr + mt * 16 + (lane >> 4) * 4 + r;
        int col = wc + nt * 16 + (lane & 15);
        outp[row * 128 + col] = acc[mt][nt][r];
      }
}

// ---------------- K2: reduce Gram partials; block0: global mean + barrier reset ----------------
__global__ void k_reduce(float* __restrict__ ws) {
  int tid = threadIdx.x;
  int idx = blockIdx.x * 256 + tid;
  const float* part = ws + fPART;
  float s = 0.f;
  #pragma unroll 8
  for (int p = 0; p < 64; p++) s += part[p * 16384 + idx];
  ws[fSWRAW + idx] = s;
  if (blockIdx.x == 0) {
    if (tid < 128) {
      const unsigned short* McT = (const unsigned short*)ws;
      float m = 0.f;
      for (int k = 0; k < 256; k++) m += bf2f(McT[tid * 256 + k]);
      ws[fMEAN + tid] = m * (1.0f / 256.0f);
    }
    if (tid == 0) *(unsigned*)(ws + fSCAL + 96) = 0u;
  }
}

// ---------------- dual-bf16 128^3 matmul phase, symmetric B-operand ----------------
// C = alpha*(*alpha_ptr)*(A*B) + beta*E1 + gamma*E2 + delta*I ; opt ||C||_F^2 partials
__device__ __forceinline__ void mm_phase(
    const unsigned short* A, const unsigned short* B, unsigned short* C,
    const unsigned short* E1, const unsigned short* E2,
    float alpha, const float* alpha_ptr, float beta, float gamma, float delta,
    float* scal, int trace_slot, float* red) {
  int tid = threadIdx.x, b = blockIdx.x;
  int w = tid >> 6, lane = tid & 63;
  int brow = b * 32, wcol = w * 32;
  f32x4 acc[2][2] = {};
  #pragma unroll
  for (int ks = 0; ks < 4; ks++) {
    int kb = ks * 32 + (lane >> 4) * 8;
    short8 ah[2], al[2], bh[2], bl[2];
    #pragma unroll
    for (int mt = 0; mt < 2; mt++) {
      int r = brow + mt * 16 + (lane & 15);
      ah[mt] = *(const short8*)(A + r * 128 + kb);
      al[mt] = *(const short8*)(A + 16384 + r * 128 + kb);
    }
    #pragma unroll
    for (int nt = 0; nt < 2; nt++) {
      int c = wcol + nt * 16 + (lane & 15);
      bh[nt] = *(const short8*)(B + c * 128 + kb);      // symmetric: row c == col c
      bl[nt] = *(const short8*)(B + 16384 + c * 128 + kb);
    }
    #pragma unroll
    for (int mt = 0; mt < 2; mt++)
      #pragma unroll
      for (int nt = 0; nt < 2; nt++) {
        f32x4 a0 = acc[mt][nt];
        a0 = __builtin_amdgcn_mfma_f32_16x16x32_bf16(ah[mt], bh[nt], a0, 0, 0, 0);
        a0 = __builtin_amdgcn_mfma_f32_16x16x32_bf16(al[mt], bh[nt], a0, 0, 0, 0);
        a0 = __builtin_amdgcn_mfma_f32_16x16x32_bf16(ah[mt], bl[nt], a0, 0, 0, 0);
        acc[mt][nt] = a0;
      }
  }
  float aeff = alpha * (alpha_ptr ? alpha_ptr[0] : 1.0f);
  float tsum = 0.0f;
  #pragma unroll
  for (int mt = 0; mt < 2; mt++)
    #pragma unroll
    for (int nt = 0; nt < 2; nt++)
      #pragma unroll
      for (int r = 0; r < 4; r++) {
        int row = brow + mt * 16 + (lane >> 4) * 4 + r;
        int col = wcol + nt * 16 + (lane & 15);
        int idx = row * 128 + col;
        float g = acc[mt][nt][r] * aeff;
        if (E1) g += beta * (bf2f(E1[idx]) + bf2f(E1[16384 + idx]));
        if (E2) g += gamma * (bf2f(E2[idx]) + bf2f(E2[16384 + idx]));
        if (row == col) g += delta;
        storeDual(C, idx, g);
        tsum += g * g;
      }
  if (trace_slot >= 0) {
    #pragma unroll
    for (int off = 32; off > 0; off >>= 1) tsum += __shfl_down(tsum, off);
    if (lane == 0) red[w] = tsum;
    __syncthreads();
    if (tid == 0) scal[trace_slot + b] = red[0] + red[1] + red[2] + red[3];
  }
}

// ---------------- K3: the whole fit, 4 blocks + grid barriers ----------------
__global__ __launch_bounds__(256) void k_fit_coop(float* __restrict__ ws) {
  __shared__ float red[4];
  float* scal = ws + fSCAL;
  unsigned* bar = (unsigned*)(scal + 96);
  const float* mv = ws + fMEAN;
  unsigned short* MATB = (unsigned short*)(ws + fMAT);
  // slots: 0 SW, 1 SB, 2 Y1, 3 Wt/Fm, 4 Qt/A1, 5 Y2, 6 Y3, 7 M1/Bq, 8 Mm, 9 C2,
  //        10 C4/B3, 11 XH, 12 T2, 13 T3, 14 T4, 15 Y5, 16-20 G0..G4, 22 B2, 23 B1
  unsigned short *SW = MATB, *SB = MATB + 1*32768, *Y1 = MATB + 2*32768,
    *Wt = MATB + 3*32768, *Qt = MATB + 4*32768, *Y2 = MATB + 5*32768,
    *Y3 = MATB + 6*32768, *M1 = MATB + 7*32768, *Mm = MATB + 8*32768,
    *C2 = MATB + 9*32768, *C4 = MATB + 10*32768, *XH = MATB + 11*32768,
    *T2 = MATB + 12*32768, *T3 = MATB + 13*32768, *T4 = MATB + 14*32768,
    *Y5 = MATB + 15*32768, *G0 = MATB + 16*32768, *G1 = MATB + 17*32768,
    *G2 = MATB + 18*32768, *G3 = MATB + 19*32768, *G4 = MATB + 20*32768,
    *B3 = MATB + 10*32768, *B2 = MATB + 22*32768, *B1 = MATB + 23*32768,
    *Fm = MATB + 3*32768, *A1 = MATB + 4*32768, *Bq = MATB + 7*32768;
  int tid = threadIdx.x, b = blockIdx.x;
  unsigned ph = 0;
  #define GBAR() do { ph++; gbar(bar, ph * NBLK); } while (0)

  // P0: SB = McT McT^T/256 - m m^T (K=256); S_w trace partials -> scal[64+b]
  {
    const unsigned short* Mc = (const unsigned short*)ws;
    const float* swraw = ws + fSWRAW;
    int w = tid >> 6, lane = tid & 63;
    int brow = b * 32, wcol = w * 32;
    f32x4 acc[2][2] = {};
    for (int ks = 0; ks < 8; ks++) {
      int kb = ks * 32 + (lane >> 4) * 8;
      short8 af[2], bfv[2];
      #pragma unroll
      for (int mt = 0; mt < 2; mt++) {
        int r = brow + mt * 16 + (lane & 15);
        af[mt] = *(const short8*)(Mc + r * 256 + kb);
      }
      #pragma unroll
      for (int nt = 0; nt < 2; nt++) {
        int c = wcol + nt * 16 + (lane & 15);
        bfv[nt] = *(const short8*)(Mc + c * 256 + kb);
      }
      #pragma unroll
      for (int mt = 0; mt < 2; mt++)
        #pragma unroll
        for (int nt = 0; nt < 2; nt++)
          acc[mt][nt] = __builtin_amdgcn_mfma_f32_16x16x32_bf16(af[mt], bfv[nt], acc[mt][nt], 0, 0, 0);
    }
    float tsum = 0.f;
    #pragma unroll
    for (int mt = 0; mt < 2; mt++)
      #pragma unroll
      for (int nt = 0; nt < 2; nt++)
        #pragma unroll
        for (int r = 0; r < 4; r++) {
          int row = brow + mt * 16 + (lane >> 4) * 4 + r;
          int col = wcol + nt * 16 + (lane & 15);
          int idx = row * 128 + col;
          float g = acc[mt][nt][r] * (1.0f / 256.0f) - mv[row] * mv[col];
          storeDual(SB, idx, g);
          if (row == col)
            tsum += swraw[row * 129] * (1.0f / COUNT) - g - mv[row] * mv[row];
        }
    #pragma unroll
    for (int off = 32; off > 0; off >>= 1) tsum += __shfl_down(tsum, off);
    if (lane == 0) red[w] = tsum;
    __syncthreads();
    if (tid == 0) scal[64 + b] = red[0] + red[1] + red[2] + red[3];
  }
  GBAR();

  // P1: SW = normalized S_w; Y1 = 1.5I - 0.5 SW
  {
    float inv_s = 128.0f / (scal[64] + scal[65] + scal[66] + scal[67]);
    const float* swraw = ws + fSWRAW;
    for (int idx = b * 256 + tid; idx < 16384; idx += 1024) {
      int row = idx >> 7, col = idx & 127;
      float sb = valU(SB, idx);
      float s = (swraw[idx] * (1.0f / COUNT) - sb - mv[row] * mv[col]) * inv_s;
      storeDual(SW, idx, s);
      storeDual(Y1, idx, ((row == col) ? 1.5f : 0.0f) - 0.5f * s);
    }
    if (b == 0 && tid == 0) scal[1] = inv_s;
  }
  GBAR();

  // Newton-Schulz sqrt (2 iterations)
  mm_phase(Y1, Y1, Wt, nullptr, nullptr, 1.0f, nullptr, 0, 0, 0.0f, scal, -1, red); GBAR();
  mm_phase(SW, Wt, Qt, nullptr, nullptr, -1.0f, nullptr, 0, 0, 3.0f, scal, -1, red); GBAR();
  mm_phase(Y1, Qt, Y2, nullptr, nullptr, 0.5f, nullptr, 0, 0, 0.0f, scal, -1, red); GBAR();
  mm_phase(Y2, Y2, Wt, nullptr, nullptr, 1.0f, nullptr, 0, 0, 0.0f, scal, -1, red); GBAR();
  mm_phase(SW, Wt, Qt, nullptr, nullptr, -1.0f, nullptr, 0, 0, 3.0f, scal, -1, red); GBAR();
  mm_phase(Y2, Qt, Y3, nullptr, nullptr, 0.5f, nullptr, 0, 0, 0.0f, scal, -1, red); GBAR();
  // M = Y*SB*Y; C2 = M^2; C4 = M^4 (+ tr(M^8) partials -> scal[68..71])
  mm_phase(Y3, SB, M1, nullptr, nullptr, 1.0f, nullptr, 0, 0, 0.0f, scal, -1, red); GBAR();
  mm_phase(M1, Y3, Mm, nullptr, nullptr, 1.0f, nullptr, 0, 0, 0.0f, scal, -1, red); GBAR();
  mm_phase(Mm, Mm, C2, nullptr, nullptr, 1.0f, nullptr, 0, 0, 0.0f, scal, -1, red); GBAR();
  mm_phase(C2, C2, C4, nullptr, nullptr, 1.0f, nullptr, 0, 0, 0.0f, scal, 68, red); GBAR();

  // P12: interval + Chebyshev coefs + bivariate transform (1 thread)
  if (b == 0 && tid == 0) {
    float s8 = scal[68] + scal[69] + scal[70] + scal[71];  // tr(M^8)
    float inv_s = scal[1];
    float Lam = 1.03f * sqrtf(sqrtf(sqrtf(fmaxf(s8, 1e-37f))));
    float lo = -0.02f * Lam, hi = Lam;
    float c0 = 0.5f * (hi + lo), h = 0.5f * (hi - lo);
    float ih = 1.0f / h;
    float t0 = (1.0f / 63.0f) / inv_s;
    float x0 = fminf(fmaxf((t0 - c0) * ih, -1.0f), 1.0f);
    float th = acosf(x0);
    float SCc = 0.984375f * inv_s * h;
    const float PI = 3.14159265358979f;
    float a[25];
    a[0] = SCc * (2.0f / PI) * (sinf(th) - x0 * th);
    a[1] = SCc * (2.0f / PI) * (0.5f * th + 0.25f * sinf(2.0f * th) - x0 * sinf(th));
    for (int j = 2; j <= 24; j++) {
      float fj = (float)j;
      a[j] = SCc * (2.0f / PI) *
          (0.5f * (sinf((fj + 1.0f) * th) / (fj + 1.0f) + sinf((fj - 1.0f) * th) / (fj - 1.0f))
           - x0 * sinf(fj * th) / fj);
    }
    float at[25];
    at[0] = 0.5f * a[0];
    for (int j = 1; j <= 24; j++) at[j] = a[j];
    float c[5][5];
    for (int k = 0; k < 5; k++) for (int r = 0; r < 5; r++) c[k][r] = 0.f;
    for (int j = 24; j >= 5; --j) {
      int k = j / 5, r = j - 5 * k;
      if (r == 0) c[k][0] += at[j];
      else { c[k][r] += 2.0f * at[j]; at[5 * k - r] -= at[j]; }
    }
    for (int r = 0; r < 5; r++) c[0][r] += at[r];
    for (int k = 0; k < 5; k++)
      for (int r = 0; r < 5; r++) scal[32 + k * 5 + r] = c[k][r];
    scal[2] = c0; scal[3] = ih;
    scal[7] = 0.984375f * inv_s;
  }
  GBAR();

  // P13: XH = ih*(M - c0 I); T2 = 2 XH^2 - I (from C2)
  {
    float c0 = scal[2], ih = scal[3];
    float a2 = 2.0f * ih * ih, b2 = -4.0f * c0 * ih * ih, g2 = 2.0f * c0 * c0 * ih * ih - 1.0f;
    for (int idx = b * 256 + tid; idx < 16384; idx += 1024) {
      int row = idx >> 7, col = idx & 127;
      float m = valU(Mm, idx), c2v = valU(C2, idx);
      float dg = (row == col) ? 1.0f : 0.0f;
      storeDual(XH, idx, ih * m - ih * c0 * dg);
      storeDual(T2, idx, a2 * c2v + b2 * m + g2 * dg);
    }
  }
  GBAR();

  // Chebyshev basis: T3 = 2 XH T2 - XH; T4 = 2 T2^2 - I; Y5 = 2 T2 T3 - XH
  mm_phase(XH, T2, T3, XH, nullptr, 2.0f, nullptr, -1.0f, 0, 0.0f, scal, -1, red); GBAR();
  mm_phase(T2, T2, T4, nullptr, nullptr, 2.0f, nullptr, 0, 0, -1.0f, scal, -1, red); GBAR();
  mm_phase(T2, T3, Y5, XH, nullptr, 2.0f, nullptr, -1.0f, 0, 0.0f, scal, -1, red); GBAR();

  // P17: G_k = sum_r c[k][r] T_r(X)
  {
    for (int idx = b * 256 + tid; idx < 16384; idx += 1024) {
      int row = idx >> 7, col = idx & 127;
      float dg = (row == col) ? 1.0f : 0.0f;
      float x1 = valU(XH, idx), x2 = valU(T2, idx), x3 = valU(T3, idx), x4 = valU(T4, idx);
      #pragma unroll
      for (int k = 0; k < 5; k++) {
        float g = scal[32 + k * 5 + 0] * dg + scal[32 + k * 5 + 1] * x1 +
                  scal[32 + k * 5 + 2] * x2 + scal[32 + k * 5 + 3] * x3 +
                  scal[32 + k * 5 + 4] * x4;
        storeDual(MATB + (16 + k) * 32768, idx, g);
      }
    }
  }
  GBAR();

  // Clenshaw in Y5 with matrix coefficients G0..G4
  mm_phase(Y5, G4, B3, G3, nullptr, 2.0f, nullptr, 1.0f, 0, 0.0f, scal, -1, red); GBAR();
  mm_phase(Y5, B3, B2, G4, G2, 2.0f, nullptr, -1.0f, 1.0f, 0.0f, scal, -1, red); GBAR();
  mm_phase(Y5, B2, B1, B3, G1, 2.0f, nullptr, -1.0f, 1.0f, 0.0f, scal, -1, red); GBAR();
  mm_phase(Y5, B1, Fm, B2, G0, 1.0f, nullptr, -1.0f, 1.0f, 0.0f, scal, 72, red); GBAR();
  // B = (63/64)*inv_s * Y*F*Y
  mm_phase(Y3, Fm, A1, nullptr, nullptr, 1.0f, nullptr, 0, 0, 0.0f, scal, -1, red); GBAR();
  mm_phase(A1, Y3, Bq, nullptr, nullptr, 1.0f, scal + 7, 0, 0, 0.0f, scal, -1, red); GBAR();

  // P24: symmetrize -> single bf16; log_div
  {
    unsigned short* Bbf = (unsigned short*)(ws + fBBF);
    for (int idx = b * 256 + tid; idx < 16384; idx += 1024) {
      int r = idx >> 7, c = idx & 127;
      Bbf[idx] = f2bf(0.5f * (valU(Bq, idx) + valU(Bq, c * 128 + r)));
    }
    if (b == 0 && tid == 0) {
      float trF2 = fmaxf(scal[72] + scal[73] + scal[74] + scal[75], 1e-30f);
      scal[0] = 0.5f * (128.0f * 1.8378770664093453f + 0.5f * logf(trF2));
    }
  }
  #undef GBAR
}

// ---------------- K4: V = test - mean (bf16); U = V*B; q_i = U_i.V_i ----------------
__global__ __launch_bounds__(256) void k_latent(const float* __restrict__ test, float* __restrict__ ws) {
  __shared__ unsigned short vh[16384];
  __shared__ float qs[128];
  int blk = blockIdx.x, tid = threadIdx.x;
  const float* tb = test + blk * 128 * D;
  unsigned short* Vbf = (unsigned short*)(ws + fV);
  if (tid < 128) qs[tid] = 0.f;
  for (int idx = tid; idx < 16384; idx += 256) {
    int r = idx >> 7, c = idx & 127;
    float v = tb[idx] - ws[fMEAN + c];
    unsigned short h = f2bf(v);
    unsigned byte = ((unsigned)(r * 256 + c * 2)) ^ (((unsigned)(r & 7)) << 4);
    *(unsigned short*)((char*)vh + byte) = h;
    Vbf[blk * 16384 + idx] = h;
  }
  __syncthreads();
  int w = tid >> 6, lane = tid & 63;
  int wr = (w >> 1) * 64, wc = (w & 1) * 64;
  const unsigned short* Bbf = (const unsigned short*)(ws + fBBF);
  f32x4 acc[4][4] = {};
  for (int ks = 0; ks < 4; ks++) {
    int kb = ks * 32 + (lane >> 4) * 8;
    short8 af[4], bfv[4];
    #pragma unroll
    for (int mt = 0; mt < 4; mt++) {
      int r = wr + mt * 16 + (lane & 15);
      unsigned byte = ((unsigned)(r * 256 + kb * 2)) ^ (((unsigned)(r & 7)) << 4);
      af[mt] = *(short8*)((char*)vh + byte);
    }
    #pragma unroll
    for (int nt = 0; nt < 4; nt++) {
      int c = wc + nt * 16 + (lane & 15);
      bfv[nt] = *(const short8*)(Bbf + c * 128 + kb); // B symmetric
    }
    #pragma unroll
    for (int mt = 0; mt < 4; mt++)
      #pragma unroll
      for (int nt = 0; nt < 4; nt++)
        acc[mt][nt] = __builtin_amdgcn_mfma_f32_16x16x32_bf16(af[mt], bfv[nt], acc[mt][nt], 0, 0, 0);
  }
  unsigned short* Ubf = (unsigned short*)(ws + fU);
  #pragma unroll
  for (int mt = 0; mt < 4; mt++)
    #pragma unroll
    for (int nt = 0; nt < 4; nt++)
      #pragma unroll
      for (int r = 0; r < 4; r++) {
        int row = wr + mt * 16 + (lane >> 4) * 4 + r;
        int col = wc + nt * 16 + (lane & 15);
        Ubf[(blk * 128 + row) * 128 + col] = f2bf(acc[mt][nt][r]);
      }
  // fused q: per-row dot of (bf16-rounded U) with V
  #pragma unroll
  for (int mt = 0; mt < 4; mt++)
    #pragma unroll
    for (int r = 0; r < 4; r++) {
      int row = wr + mt * 16 + (lane >> 4) * 4 + r;
      float p = 0.f;
      #pragma unroll
      for (int nt = 0; nt < 4; nt++) {
        int col = wc + nt * 16 + (lane & 15);
        unsigned byte = ((unsigned)(row * 256 + col * 2)) ^ (((unsigned)(row & 7)) << 4);
        p += bf2f(f2bf(acc[mt][nt][r])) * bf2f(*(unsigned short*)((char*)vh + byte));
      }
      p += __shfl_xor(p, 1, 16);
      p += __shfl_xor(p, 2, 16);
      p += __shfl_xor(p, 4, 16);
      p += __shfl_xor(p, 8, 16);
      if ((lane & 15) == 0) atomicAdd(&qs[row], p);  // exactly 2 adds/row: deterministic
    }
  __syncthreads();
  if (tid < 128) ws[fQ + blk * 128 + tid] = qs[tid];
}

// ---------------- K5: out = 2 U V^T - q_i - q_j - log_div ----------------
__global__ __launch_bounds__(256) void k_pair(const float* __restrict__ ws, float* __restrict__ out) {
  __shared__ float qi[128];
  __shared__ float qj[128];
  __shared__ float sld;
  int bi = blockIdx.x, bj = blockIdx.y, tid = threadIdx.x;
  if (tid < 128) qi[tid] = ws[fQ + bi * 128 + tid];
  else qj[tid - 128] = ws[fQ + bj * 128 + (tid - 128)];
  if (tid == 0) sld = ws[fSCAL + 0];
  __syncthreads();
  int w = tid >> 6, lane = tid & 63;
  int wr = (w >> 1) * 64, wc = (w & 1) * 64;
  const unsigned short* Ubf = (const unsigned short*)(ws + fU);
  const unsigned short* Vbf = (const unsigned short*)(ws + fV);
  f32x4 acc[4][4] = {};
  for (int ks = 0; ks < 4; ks++) {
    int kb = ks * 32 + (lane >> 4) * 8;
    short8 af[4], bfv[4];
    #pragma unroll
    for (int mt = 0; mt < 4; mt++) {
      int r = bi * 128 + wr + mt * 16 + (lane & 15);
      af[mt] = *(const short8*)(Ubf + r * 128 + kb);
    }
    #pragma unroll
    for (int nt = 0; nt < 4; nt++) {
      int c = bj * 128 + wc + nt * 16 + (lane & 15);
      bfv[nt] = *(const short8*)(Vbf + c * 128 + kb);
    }
    #pragma unroll
    for (int mt = 0; mt < 4; mt++)
      #pragma unroll
      for (int nt = 0; nt < 4; nt++)
        acc[mt][nt] = __builtin_amdgcn_mfma_f32_16x16x32_bf16(af[mt], bfv[nt], acc[mt][nt], 0, 0, 0);
  }
  float ld = sld;
  #pragma unroll
  for (int mt = 0; mt < 4; mt++)
    #pragma unroll
    for (int nt = 0; nt < 4; nt++)
      #pragma unroll
      for (int r = 0; r < 4; r++) {
        int row = wr + mt * 16 + (lane >> 4) * 4 + r;
        int col = wc + nt * 16 + (lane & 15);
        float g = acc[mt][nt][r];
        out[(size_t)(bi * 128 + row) * MTEST + (bj * 128 + col)] =
          2.0f * g - qi[row] - qj[col] - ld;
      }
}

extern "C" void kernel_launch(void* const* d_in, const int* in_sizes, int n_in,
                              void* d_out, int out_size, void* d_ws, size_t ws_size,
                              hipStream_t stream) {
  (void)in_sizes; (void)n_in; (void)out_size; (void)ws_size;
  const float* X = (const float*)d_in[0];
  const float* test = (const float*)d_in[1];
  float* out = (float*)d_out;
  float* ws = (float*)d_ws;

  k_gt_partial<<<64, 256, 0, stream>>>(X, ws);   // Gram partials + class means
  k_reduce<<<64, 256, 0, stream>>>(ws);          // Gram sum + global mean + bar reset
  k_fit_coop<<<NBLK, 256, 0, stream>>>(ws);      // entire fit, 25 phases
  k_latent<<<64, 256, 0, stream>>>(test, ws);    // V, U, q
  k_pair<<<dim3(64, 64), 256, 0, stream>>>(ws, out);
}